// Round 16
// baseline (3788.394 us; speedup 1.0000x reference)
//
#include <hip/hip_runtime.h>
#include <math.h>

#define SEQ 197
#define BATCH 32
#define DIM 256
#define NHEAD 8
#define HDIM 32
#define NEXP 8
#define NLAYER 4
#define FFDIM 1024
#define NCLS 1000
#define NPATCH 196
#define TOK (BATCH * SEQ) /* 6304 */
#define CAP 13120         /* 2*TOK + 8*64 segment padding */
#define YB 99             /* ceil(TOK/64) */
#define YB128 50          /* ceil(TOK/128) */
#define KT 64             /* attention key tile */

// ------------------------------------------------- global->LDS direct DMA ---
__device__ __forceinline__ void gload16(const float* g, float* l) {
  __builtin_amdgcn_global_load_lds(
      (const __attribute__((address_space(1))) void*)g,
      (__attribute__((address_space(3))) void*)l, 16, 0, 0);
}

// ---------------------------------------------------------------- im2col ----
__global__ __launch_bounds__(256) void k_im2col(const float* __restrict__ x,
                                                float* __restrict__ Apat) {
  int idx = blockIdx.x * 256 + threadIdx.x;
  if (idx >= BATCH * NPATCH * 768) return;
  int cpp = idx % 768;
  int m = idx / 768;
  int n = m % NPATCH;
  int b = m / NPATCH;
  int c = cpp >> 8;
  int py = (cpp >> 4) & 15;
  int px = cpp & 15;
  int gy = n / 14, gx = n % 14;
  Apat[idx] = x[(((size_t)b * 3 + c) * 224 + gy * 16 + py) * 224 + gx * 16 + px];
}

// --------------------------------------------- fold ln1 affine into qkv_w ---
__global__ __launch_bounds__(256) void k_foldw(const float* __restrict__ qw,
                                               const float* __restrict__ g1,
                                               float* __restrict__ w4) {
  size_t idx = (size_t)blockIdx.x * 256 + threadIdx.x;
  if (idx >= (size_t)32 * 256 * 768) return;
  size_t kn = idx % (256 * 768);
  int le = (int)(idx / (256 * 768));
  int k = (int)(kn / 768);
  w4[idx] = qw[idx] * g1[le * 256 + k];
}

__global__ __launch_bounds__(256) void k_foldb(const float* __restrict__ qw,
                                               const float* __restrict__ qb,
                                               const float* __restrict__ b1,
                                               float* __restrict__ b4) {
  int le = blockIdx.y;
  int col = blockIdx.x * 256 + threadIdx.x; /* < 768 */
  const float* w = qw + (size_t)le * 256 * 768 + col;
  const float* lb = b1 + (size_t)le * 256;
  float acc = 0.f;
  for (int k = 0; k < 256; ++k) acc = fmaf(lb[k], w[(size_t)k * 768], acc);
  b4[(size_t)le * 768 + col] = acc + qb[(size_t)le * 768 + col];
}

// ------------------------------------------------------------ GEMM (4x8) ----
// 64x128 tile, BK=32, 256 threads, 4x8/thread, both operands via
// global_load_lds DMA. COUNTED-VMCNT 2-deep pipeline (T3/T4 minimum form):
// raw s_barrier + inline-asm s_waitcnt vmcnt(6) -- prefetched loads stay in
// flight across barriers instead of the compiler's vmcnt(0) drain (the
// documented m97-structure stall). Race-free: tile i+2's loads into buf p
// are issued only AFTER the barrier proving all waves finished reading
// buf p. Exactly 6 vmem loads/wave/tile -> vmcnt(6) == "previous tile
// complete". Used for patch / Q / proj / fc2.
// flags bit0 = segmented rows (off_e/cnt_e), bit1 = gather A row via ptok.
// mode 0: out[row] = v   1: out[gr]=v+R[tok]   2: out[gr]=gelu(v)
// mode 3: atomicAdd(out[tok], PW[gr]*(X2[gr]+v))
__global__ __launch_bounds__(256) void k_gemm_t(
    const float* __restrict__ A, const float* __restrict__ W,
    const float* __restrict__ bias, const float* __restrict__ R,
    const float* __restrict__ X2, const float* __restrict__ PW,
    const int* __restrict__ ptok, const int* __restrict__ off_e,
    const int* __restrict__ cnt_e, float* __restrict__ out, int M, int N,
    int K, int Wld, int wcol, int bstride, int ebase, int mode, int flags) {
  __shared__ float As[2][2][64][16]; /* [dbuf][k-half][row][k] */
  __shared__ float Bs[2][32][128];
  int gx = gridDim.x, gy = gridDim.y;
  int nwg = gx * gy * gridDim.z;
  int lin = blockIdx.x + gx * (blockIdx.y + gy * blockIdx.z);
  int q8 = nwg >> 3, r8 = nwg & 7;
  int xcd = lin & 7, jj0 = lin >> 3;
  int nlin = (xcd < r8 ? xcd * (q8 + 1) : r8 * (q8 + 1) + (xcd - r8) * q8) + jj0;
  int bx = nlin % gx;
  int t1 = nlin / gx;
  int by = t1 % gy;
  int bz = t1 / gy;

  int e = ebase + bz;
  bool seg = (flags & 1) != 0;
  int rows = seg ? cnt_e[e] : M;
  int row0 = by * 64;
  if (row0 >= rows) return;
  int col0 = bx * 128;
  int tid = threadIdx.x;
  int wv = tid >> 6, lane = tid & 63;
  int base = seg ? off_e[e] : 0;
  const float* Wp = W + (size_t)e * K * Wld + wcol;
  const float* bp = bias + (size_t)e * bstride + wcol;

  // A DMA: wave wv covers rows row0+wv*16..+15 of each k-half; lane l ->
  // row +(l>>2), k-offset (l&3)*4 (half 1 at +16).
  const float* pA;
  {
    int r = row0 + wv * 16 + (lane >> 2);
    int rc = r < rows ? r : rows - 1; /* rows >= 1 since row0 < rows */
    int gr0 = base + rc;
    int arow = seg ? ((flags & 2) ? ptok[gr0] : gr0) : rc;
    pA = A + (size_t)arow * K + (lane & 3) * 4;
  }
  // B DMA: wave wv stages rows wv*8 + 2c (+ l>>5), c = 0..3; lane l ->
  // col (l&31)*4.
  const float* pB =
      Wp + (size_t)(wv * 8 + (lane >> 5)) * Wld + col0 + (lane & 31) * 4;

  auto issue = [&](int t, int b) {
    gload16(pA + t * 32, &As[b][0][wv * 16][0]);
    gload16(pA + t * 32 + 16, &As[b][1][wv * 16][0]);
#pragma unroll
    for (int c = 0; c < 4; ++c)
      gload16(pB + (size_t)(t * 32 + c * 2) * Wld, &Bs[b][wv * 8 + c * 2][0]);
  };

  int nt = K >> 5; /* tiles of BK=32; >= 8 for all call sites */
  // prologue: 2-deep — issue tiles 0 and 1, wait only for tile 0 (vmcnt 6)
  issue(0, 0);
  issue(1, 1);
  asm volatile("s_waitcnt vmcnt(6)" ::: "memory");
  __builtin_amdgcn_sched_barrier(0);
  __builtin_amdgcn_s_barrier();

  int tx = tid & 15, ty = tid >> 4;
  float acc0[4][4] = {};
  float acc1[4][4] = {};
  int p = 0;
  for (int i = 0; i < nt; ++i) {
#pragma unroll
    for (int h = 0; h < 2; ++h) {
#pragma unroll
      for (int k4 = 0; k4 < 4; ++k4) {
        float a[4][4];
#pragma unroll
        for (int ii = 0; ii < 4; ++ii) {
          float4 t = *(const float4*)&As[p][h][ty + 16 * ii][k4 * 4];
          a[ii][0] = t.x;
          a[ii][1] = t.y;
          a[ii][2] = t.z;
          a[ii][3] = t.w;
        }
#pragma unroll
        for (int kk = 0; kk < 4; ++kk) {
          int kr = h * 16 + k4 * 4 + kk;
          float4 b0 = *(const float4*)&Bs[p][kr][tx * 4];
          float4 b1 = *(const float4*)&Bs[p][kr][64 + tx * 4];
          float b0a[4] = {b0.x, b0.y, b0.z, b0.w};
          float b1a[4] = {b1.x, b1.y, b1.z, b1.w};
#pragma unroll
          for (int ii = 0; ii < 4; ++ii) {
            float av = a[ii][kk];
#pragma unroll
            for (int j = 0; j < 4; ++j) {
              acc0[ii][j] = fmaf(av, b0a[j], acc0[ii][j]);
              acc1[ii][j] = fmaf(av, b1a[j], acc1[ii][j]);
            }
          }
        }
      }
    }
    if (i + 1 < nt) {
      /* all ds_read results consumed; make overwrite of buf p legal */
      asm volatile("s_waitcnt lgkmcnt(0)" ::: "memory");
      __builtin_amdgcn_sched_barrier(0);
      __builtin_amdgcn_s_barrier(); /* no wave still reads buf p */
      __builtin_amdgcn_sched_barrier(0);
      if (i + 2 < nt) {
        issue(i + 2, p); /* overwrite freed buffer */
        asm volatile("s_waitcnt vmcnt(6)" ::: "memory"); /* tile i+1 done */
      } else {
        asm volatile("s_waitcnt vmcnt(0)" ::: "memory"); /* tail drain */
      }
      __builtin_amdgcn_sched_barrier(0);
      __builtin_amdgcn_s_barrier(); /* buf p^1 valid for all waves */
      __builtin_amdgcn_sched_barrier(0);
      p ^= 1;
    }
  }
#pragma unroll
  for (int i = 0; i < 4; ++i) {
    int rrow = row0 + ty + 16 * i;
    if (rrow >= rows) continue;
    int gr = base + rrow;
#pragma unroll
    for (int c = 0; c < 2; ++c) {
#pragma unroll
      for (int j = 0; j < 4; ++j) {
        int col = col0 + c * 64 + tx * 4 + j;
        float v = (c ? acc1[i][j] : acc0[i][j]) + bp[col];
        if (mode == 0) {
          size_t orow = seg ? (size_t)gr : (size_t)bz * M + rrow;
          out[orow * N + col] = v;
        } else if (mode == 1) {
          int t = ptok[gr];
          out[(size_t)gr * N + col] = v + R[(size_t)t * N + col];
        } else if (mode == 2) {
          out[(size_t)gr * N + col] =
              0.5f * v * (1.f + erff(v * 0.70710678118654752f));
        } else {
          int t = ptok[gr];
          atomicAdd(&out[(size_t)t * N + col],
                    PW[gr] * (X2[(size_t)gr * N + col] + v));
        }
      }
    }
  }
}

// ------------------------------------------------------------ GEMM (16x8) ---
// 128x128x16 tile, 256 threads (4 waves), 8x8/thread. Both A and B staged by
// global_load_lds DMA. Used for the block-rich dense GEMMs: KV / fc1.
__global__ __launch_bounds__(256) void k_gemm16(
    const float* __restrict__ A, const float* __restrict__ W,
    const float* __restrict__ bias, const float* __restrict__ R,
    const float* __restrict__ X2, const float* __restrict__ PW,
    const int* __restrict__ ptok, const int* __restrict__ off_e,
    const int* __restrict__ cnt_e, float* __restrict__ out, int M, int N,
    int K, int Wld, int wcol, int bstride, int ebase, int mode, int flags) {
  __shared__ float As[2][128][16];
  __shared__ float Bs[2][16][128];
  int gx = gridDim.x, gy = gridDim.y;
  int nwg = gx * gy * gridDim.z;
  int lin = blockIdx.x + gx * (blockIdx.y + gy * blockIdx.z);
  int q8 = nwg >> 3, r8 = nwg & 7;
  int xcd = lin & 7, jj0 = lin >> 3;
  int nlin = (xcd < r8 ? xcd * (q8 + 1) : r8 * (q8 + 1) + (xcd - r8) * q8) + jj0;
  int bx = nlin % gx;
  int t1 = nlin / gx;
  int by = t1 % gy;
  int bz = t1 / gy;

  int e = ebase + bz;
  bool seg = (flags & 1) != 0;
  int rows = seg ? cnt_e[e] : M;
  int row0 = by * 128;
  if (row0 >= rows) return;
  int col0 = bx * 128;
  int tid = threadIdx.x;
  int wv = tid >> 6, lane = tid & 63;
  int base = seg ? off_e[e] : 0;
  const float* Wp = W + (size_t)e * K * Wld + wcol;
  const float* bp = bias + (size_t)e * bstride + wcol;

  const float* pA0;
  const float* pA1;
  {
    int l4 = lane >> 2, lk = (lane & 3) * 4;
#pragma unroll
    for (int c = 0; c < 2; ++c) {
      int r = row0 + wv * 32 + c * 16 + l4;
      int rc = r < rows ? r : rows - 1;
      int gr0 = base + rc;
      int arow = seg ? ((flags & 2) ? ptok[gr0] : gr0) : rc;
      const float* p = A + (size_t)arow * K + lk;
      if (c == 0) pA0 = p; else pA1 = p;
    }
  }
  const float* pB = Wp + (size_t)(4 * wv + (lane >> 5)) * Wld + col0 +
                    (lane & 31) * 4;

  gload16(pA0, &As[0][wv * 32][0]);
  gload16(pA1, &As[0][wv * 32 + 16][0]);
  gload16(pB, &Bs[0][4 * wv][0]);
  gload16(pB + (size_t)2 * Wld, &Bs[0][4 * wv + 2][0]);
  __syncthreads();

  int tx = tid & 15, ty = tid >> 4; /* ty 0..15 */
  float acc0[8][4] = {};
  float acc1[8][4] = {};
  int cur = 0;
  for (int k0 = 0; k0 < K; k0 += 16) {
    int nb = cur ^ 1;
    bool more = (k0 + 16) < K;
    if (more) {
      gload16(pA0 + k0 + 16, &As[nb][wv * 32][0]);
      gload16(pA1 + k0 + 16, &As[nb][wv * 32 + 16][0]);
      gload16(pB + (size_t)(k0 + 16) * Wld, &Bs[nb][4 * wv][0]);
      gload16(pB + (size_t)(k0 + 18) * Wld, &Bs[nb][4 * wv + 2][0]);
    }
#pragma unroll
    for (int k4 = 0; k4 < 4; ++k4) {
      float a[8][4];
#pragma unroll
      for (int i = 0; i < 8; ++i) {
        float4 t = *(const float4*)&As[cur][ty + 16 * i][k4 * 4];
        a[i][0] = t.x;
        a[i][1] = t.y;
        a[i][2] = t.z;
        a[i][3] = t.w;
      }
#pragma unroll
      for (int kk = 0; kk < 4; ++kk) {
        float4 b0 = *(const float4*)&Bs[cur][k4 * 4 + kk][tx * 4];
        float4 b1 = *(const float4*)&Bs[cur][k4 * 4 + kk][64 + tx * 4];
        float b0a[4] = {b0.x, b0.y, b0.z, b0.w};
        float b1a[4] = {b1.x, b1.y, b1.z, b1.w};
#pragma unroll
        for (int i = 0; i < 8; ++i) {
          float av = a[i][kk];
#pragma unroll
          for (int j = 0; j < 4; ++j) {
            acc0[i][j] = fmaf(av, b0a[j], acc0[i][j]);
            acc1[i][j] = fmaf(av, b1a[j], acc1[i][j]);
          }
        }
      }
    }
    __syncthreads();
    cur = nb;
  }
#pragma unroll
  for (int i = 0; i < 8; ++i) {
    int rrow = row0 + ty + 16 * i;
    if (rrow >= rows) continue;
    int gr = base + rrow;
#pragma unroll
    for (int c = 0; c < 2; ++c) {
#pragma unroll
      for (int j = 0; j < 4; ++j) {
        int col = col0 + c * 64 + tx * 4 + j;
        float v = (c ? acc1[i][j] : acc0[i][j]) + bp[col];
        if (mode == 0) {
          size_t orow = seg ? (size_t)gr : (size_t)bz * M + rrow;
          out[orow * N + col] = v;
        } else if (mode == 1) {
          int t = ptok[gr];
          out[(size_t)gr * N + col] = v + R[(size_t)t * N + col];
        } else if (mode == 2) {
          out[(size_t)gr * N + col] =
              0.5f * v * (1.f + erff(v * 0.70710678118654752f));
        } else {
          int t = ptok[gr];
          atomicAdd(&out[(size_t)t * N + col],
                    PW[gr] * (X2[(size_t)gr * N + col] + v));
        }
      }
    }
  }
}

// ------------------------------------------------------------- assemble h ---
__global__ __launch_bounds__(256) void k_assemble(const float* __restrict__ tmp,
                                                  const float* __restrict__ cls,
                                                  const float* __restrict__ pos,
                                                  float* __restrict__ h) {
  int idx = blockIdx.x * 256 + threadIdx.x;
  if (idx >= TOK * DIM) return;
  int d = idx & 255;
  int t = idx >> 8;
  int s = t % SEQ;
  int b = t / SEQ;
  float v = (s == 0) ? cls[d] : tmp[((size_t)b * NPATCH + s - 1) * DIM + d];
  h[idx] = v + pos[s * DIM + d];
}

// ------------------------------------------------------------------ router --
__global__ __launch_bounds__(64) void k_router(
    const float* __restrict__ h, const float* __restrict__ rw,
    const float* __restrict__ rb, int* __restrict__ cnt_eb,
    int* __restrict__ tmp_s, float* __restrict__ tmp_w) {
  int t = blockIdx.x;
  int lane = threadIdx.x;
  float hv[4];
  const float* hp = h + (size_t)t * DIM + lane * 4;
#pragma unroll
  for (int i = 0; i < 4; i++) hv[i] = hp[i];
  float lg[8];
#pragma unroll
  for (int e = 0; e < 8; e++) {
    float p = 0.f;
#pragma unroll
    for (int i = 0; i < 4; i++) p = fmaf(hv[i], rw[(lane * 4 + i) * 8 + e], p);
#pragma unroll
    for (int off = 32; off; off >>= 1) p += __shfl_down(p, off);
    lg[e] = p;
  }
  if (lane == 0) {
#pragma unroll
    for (int e = 0; e < 8; e++) lg[e] += rb[e];
    float mx = lg[0];
#pragma unroll
    for (int e = 1; e < 8; e++) mx = fmaxf(mx, lg[e]);
    float pr[8];
#pragma unroll
    for (int e = 0; e < 8; e++) pr[e] = expf(lg[e] - mx);
    int i0 = 0;
#pragma unroll
    for (int e = 1; e < 8; e++)
      if (pr[e] > pr[i0]) i0 = e;
    int i1 = -1;
#pragma unroll
    for (int e = 0; e < 8; e++)
      if (e != i0 && (i1 < 0 || pr[e] > pr[i1])) i1 = e;
    float wsum = pr[i0] + pr[i1];
    int b = t / SEQ, s = t - b * SEQ;
    int eb0 = i0 * 32 + b;
    int p0 = atomicAdd(&cnt_eb[eb0], 1);
    tmp_s[eb0 * SEQ + p0] = s;
    tmp_w[eb0 * SEQ + p0] = pr[i0] / wsum;
    int eb1 = i1 * 32 + b;
    int p1 = atomicAdd(&cnt_eb[eb1], 1);
    tmp_s[eb1 * SEQ + p1] = s;
    tmp_w[eb1 * SEQ + p1] = pr[i1] / wsum;
  }
}

// --------------------------------------------------------------- scan -------
__global__ __launch_bounds__(64) void k_scan(const int* __restrict__ cnt_eb,
                                             int* __restrict__ off_eb,
                                             int* __restrict__ off_e,
                                             int* __restrict__ cnt_e) {
  if (threadIdx.x == 0 && blockIdx.x == 0) {
    int g = 0;
    for (int e = 0; e < 8; e++) {
      off_e[e] = g;
      int ce = 0;
      for (int b = 0; b < 32; b++) {
        off_eb[e * 32 + b] = g + ce;
        ce += cnt_eb[e * 32 + b];
      }
      cnt_e[e] = ce;
      g += (ce + 63) & ~63;
    }
  }
}

__global__ __launch_bounds__(256) void k_scatter(
    const int* __restrict__ cnt_eb, const int* __restrict__ off_eb,
    const int* __restrict__ tmp_s, const float* __restrict__ tmp_w,
    int* __restrict__ ptok, float* __restrict__ pw) {
  int eb = blockIdx.x;
  int b = eb & 31;
  int c = cnt_eb[eb];
  int o = off_eb[eb];
  for (int i = threadIdx.x; i < c; i += 256) {
    ptok[o + i] = b * SEQ + tmp_s[eb * SEQ + i];
    pw[o + i] = tmp_w[eb * SEQ + i];
  }
}

// -------------------------------------------------------------- layernorm ---
__global__ __launch_bounds__(256) void k_ln_noaff(const float* __restrict__ X,
                                                  float* __restrict__ Y) {
  int t = blockIdx.x;
  int d = threadIdx.x;
  float v = X[(size_t)t * DIM + d];
  __shared__ float red[4];
  float s = v;
#pragma unroll
  for (int o = 32; o; o >>= 1) s += __shfl_down(s, o);
  if ((d & 63) == 0) red[d >> 6] = s;
  __syncthreads();
  float mean = (red[0] + red[1] + red[2] + red[3]) * (1.f / 256.f);
  __syncthreads();
  float c = v - mean;
  float s2 = c * c;
#pragma unroll
  for (int o = 32; o; o >>= 1) s2 += __shfl_down(s2, o);
  if ((d & 63) == 0) red[d >> 6] = s2;
  __syncthreads();
  float var = (red[0] + red[1] + red[2] + red[3]) * (1.f / 256.f);
  Y[(size_t)t * DIM + d] = c * rsqrtf(var + 1e-5f);
}

__global__ __launch_bounds__(256) void k_ln_seg(
    const float* __restrict__ X, const float* __restrict__ g,
    const float* __restrict__ bta, float* __restrict__ Y,
    const int* __restrict__ off_e, const int* __restrict__ cnt_e) {
  int e = blockIdx.y;
  int cnt = cnt_e[e];
  int base = off_e[e];
  int d = threadIdx.x;
  float gv = g[e * DIM + d];
  float bv = bta[e * DIM + d];
  __shared__ float red[4];
  for (int r = blockIdx.x; r < cnt; r += gridDim.x) {
    size_t gr = (size_t)(base + r);
    float v = X[gr * DIM + d];
    float s = v;
#pragma unroll
    for (int o = 32; o; o >>= 1) s += __shfl_down(s, o);
    if ((d & 63) == 0) red[d >> 6] = s;
    __syncthreads();
    float mean = (red[0] + red[1] + red[2] + red[3]) * (1.f / 256.f);
    __syncthreads();
    float c = v - mean;
    float s2 = c * c;
#pragma unroll
    for (int o = 32; o; o >>= 1) s2 += __shfl_down(s2, o);
    if ((d & 63) == 0) red[d >> 6] = s2;
    __syncthreads();
    float var = (red[0] + red[1] + red[2] + red[3]) * (1.f / 256.f);
    Y[gr * DIM + d] = c * rsqrtf(var + 1e-5f) * gv + bv;
    __syncthreads();
  }
}

// -------------------------------------------------------------- attention ---
// block = (expert-slot, batch, head). K/V staged in 64-key LDS tiles (16 KB
// -> 8 blocks/CU). 4-lane quad per query; branchless online softmax.
__global__ __launch_bounds__(256) void k_attn(
    const float* __restrict__ qc, const float* __restrict__ kv,
    float* __restrict__ oc, const int* __restrict__ cnt_eb,
    const int* __restrict__ off_eb, int ebase) {
  int bx = blockIdx.x;
  int hh = bx & 7;
  int b = (bx >> 3) & 31;
  int ez = bx >> 8;
  int eb = (ebase + ez) * 32 + b;
  int cnt = cnt_eb[eb];
  if (cnt == 0) return;
  int off = off_eb[eb];
  __shared__ float Ks[KT][HDIM];
  __shared__ float Vs[KT][HDIM];
  const float* base = kv + ((size_t)ez * TOK + (size_t)b * SEQ) * 512;
  int tid = threadIdx.x;
  int grp = tid >> 2; /* 0..63 query slot */
  int ln = tid & 3;   /* quad lane: dims [ln*8, ln*8+8) */
  int nrounds = (cnt + 63) >> 6;
  for (int qr = 0; qr < nrounds; ++qr) {
    int qi = qr * 64 + grp;
    bool act = qi < cnt;
    int qc_i = act ? qi : cnt - 1;
    const float* qp = qc + (size_t)(off + qc_i) * DIM + hh * HDIM + ln * 8;
    float4 q0 = *(const float4*)qp;
    float4 q1 = *(const float4*)(qp + 4);
    float qv[8] = {q0.x, q0.y, q0.z, q0.w, q1.x, q1.y, q1.z, q1.w};
    float m = -1e30f, l = 0.f;
    float acc[8] = {};
    for (int t0 = 0; t0 < SEQ; t0 += KT) {
      int nk = (SEQ - t0) < KT ? (SEQ - t0) : KT;
      __syncthreads();
      for (int i = tid; i < nk * 16; i += 256) {
        int row = i >> 4, half = (i >> 3) & 1, c4 = (i & 7) * 4;
        const float* p =
            base + (size_t)(t0 + row) * 512 + half * 256 + hh * HDIM + c4;
        if (half == 0)
          *(float4*)&Ks[row][c4] = *(const float4*)p;
        else
          *(float4*)&Vs[row][c4] = *(const float4*)p;
      }
      __syncthreads();
      const float* KsL = &Ks[0][ln * 8];
      const float* VsL = &Vs[0][ln * 8];
#pragma unroll 2
      for (int j = 0; j < nk; ++j) {
        const float4* kr = (const float4*)(KsL + j * HDIM);
        float4 k0 = kr[0], k1 = kr[1];
        float s = qv[0] * k0.x;
        s = fmaf(qv[1], k0.y, s);
        s = fmaf(qv[2], k0.z, s);
        s = fmaf(qv[3], k0.w, s);
        s = fmaf(qv[4], k1.x, s);
        s = fmaf(qv[5], k1.y, s);
        s = fmaf(qv[6], k1.z, s);
        s = fmaf(qv[7], k1.w, s);
        s += __shfl_xor(s, 1);
        s += __shfl_xor(s, 2);
        s *= 0.17677669529663687f; /* 1/sqrt(32) */
        float nm = fmaxf(m, s);
        float f = expf(m - nm);
        float e2 = expf(s - nm);
        m = nm;
        l = fmaf(l, f, e2);
        const float4* vr = (const float4*)(VsL + j * HDIM);
        float4 v0 = vr[0], v1 = vr[1];
        acc[0] = fmaf(acc[0], f, e2 * v0.x);
        acc[1] = fmaf(acc[1], f, e2 * v0.y);
        acc[2] = fmaf(acc[2], f, e2 * v0.z);
        acc[3] = fmaf(acc[3], f, e2 * v0.w);
        acc[4] = fmaf(acc[4], f, e2 * v1.x);
        acc[5] = fmaf(acc[5], f, e2 * v1.y);
        acc[6] = fmaf(acc[6], f, e2 * v1.z);
        acc[7] = fmaf(acc[7], f, e2 * v1.w);
      }
    }
    if (act) {
      float inv = 1.f / l;
      float* op = oc + (size_t)(off + qi) * DIM + hh * HDIM + ln * 8;
      float4 o0 = {acc[0] * inv, acc[1] * inv, acc[2] * inv, acc[3] * inv};
      float4 o1 = {acc[4] * inv, acc[5] * inv, acc[6] * inv, acc[7] * inv};
      *(float4*)op = o0;
      *(float4*)(op + 4) = o1;
    }
  }
}

// ------------------------------------------------------------- final head ---
__global__ __launch_bounds__(256) void k_head(const float* __restrict__ h,
                                              const float* __restrict__ ng,
                                              const float* __restrict__ nb,
                                              const float* __restrict__ hw,
                                              const float* __restrict__ hb,
                                              float* __restrict__ out) {
  int b = blockIdx.x;
  int d = threadIdx.x;
  float v = h[(size_t)b * SEQ * DIM + d];
  __shared__ float red[4];
  __shared__ float hls[DIM];
  float s = v;
#pragma unroll
  for (int off = 32; off; off >>= 1) s += __shfl_down(s, off);
  if ((d & 63) == 0) red[d >> 6] = s;
  __syncthreads();
  float mean = (red[0] + red[1] + red[2] + red[3]) * (1.f / 256.f);
  __syncthreads();
  float c = v - mean;
  float s2 = c * c;
#pragma unroll
  for (int off = 32; off; off >>= 1) s2 += __shfl_down(s2, off);
  if ((d & 63) == 0) red[d >> 6] = s2;
  __syncthreads();
  float var = (red[0] + red[1] + red[2] + red[3]) * (1.f / 256.f);
  hls[d] = c * rsqrtf(var + 1e-5f) * ng[d] + nb[d];
  __syncthreads();
  for (int j = d; j < NCLS; j += 256) {
    float sdot = hb[j];
    for (int k2 = 0; k2 < DIM; k2++)
      sdot = fmaf(hls[k2], hw[(size_t)k2 * NCLS + j], sdot);
    out[(size_t)b * NCLS + j] = sdot;
  }
}

// ---------------------------------------------------------------- launch ----
extern "C" void kernel_launch(void* const* d_in, const int* in_sizes, int n_in,
                              void* d_out, int out_size, void* d_ws,
                              size_t ws_size, hipStream_t stream) {
  const float* x = (const float*)d_in[0];
  const float* patch_w = (const float*)d_in[1];
  const float* patch_b = (const float*)d_in[2];
  const float* cls_token = (const float*)d_in[3];
  const float* pos_embed = (const float*)d_in[4];
  const float* router_w = (const float*)d_in[5];
  const float* router_b = (const float*)d_in[6];
  const float* ln1_g = (const float*)d_in[7];
  const float* ln1_b = (const float*)d_in[8];
  const float* qkv_w = (const float*)d_in[9];
  const float* qkv_b = (const float*)d_in[10];
  const float* proj_w = (const float*)d_in[11];
  const float* proj_b = (const float*)d_in[12];
  const float* ln2_g = (const float*)d_in[13];
  const float* ln2_b = (const float*)d_in[14];
  const float* fc1_w = (const float*)d_in[15];
  const float* fc1_b = (const float*)d_in[16];
  const float* fc2_w = (const float*)d_in[17];
  const float* fc2_b = (const float*)d_in[18];
  const float* norm_g = (const float*)d_in[19];
  const float* norm_b = (const float*)d_in[20];
  const float* head_w = (const float*)d_in[21];
  const float* head_b = (const float*)d_in[22];

  float* ws = (float*)d_ws;
  size_t off = 0;
  float* xhat = ws + off; off += (size_t)TOK * DIM;
  float* hbuf = ws + off; off += (size_t)TOK * DIM;
  float* accb = ws + off; off += (size_t)TOK * DIM;
  float* qc   = ws + off; off += (size_t)CAP * DIM;   /* also hln (aliased) */
  float* oc   = ws + off; off += (size_t)CAP * DIM;
  float* x2c  = ws + off; off += (size_t)CAP * DIM;
  float* ffc  = ws + off; off += (size_t)CAP * FFDIM; /* also im2col + kv4 */
  float* w4   = ws + off; off += (size_t)32 * DIM * 768; /* folded qkv W */
  float* b4   = ws + off; off += (size_t)32 * 768;       /* folded qkv b */
  float* pwb  = ws + off; off += CAP;
  float* tmpw = ws + off; off += 256 * SEQ;
  int* ptok   = (int*)(ws + off); off += CAP;
  int* tmps   = (int*)(ws + off); off += 256 * SEQ;
  int* cnt_eb = (int*)(ws + off); off += 256;
  int* off_eb = (int*)(ws + off); off += 256;
  int* off_e  = (int*)(ws + off); off += 8;
  int* cnt_e  = (int*)(ws + off); off += 8;
  float* kv4 = ffc;   /* 4*TOK*512 = 12.9M floats <= CAP*FFDIM = 13.4M */
  float* hlnc = qc;   /* qc dead after attention; hln live ln2->fc1 */

  // ---- one-time: fold ln1 affine into qkv weights ----
  k_foldw<<<(32 * 256 * 768 + 255) / 256, 256, 0, stream>>>(qkv_w, ln1_g, w4);
  k_foldb<<<dim3(3, 32), 256, 0, stream>>>(qkv_w, qkv_b, ln1_b, b4);

  // ---- patch embed ----
  int tot = BATCH * NPATCH * 768;
  k_im2col<<<(tot + 255) / 256, 256, 0, stream>>>(x, ffc);
  k_gemm_t<<<dim3(2, 98, 1), 256, 0, stream>>>(
      ffc, patch_w, patch_b, nullptr, nullptr, nullptr, nullptr, nullptr,
      nullptr, qc, BATCH * NPATCH, DIM, 768, DIM, 0, 0, 0, 0, 0);
  k_assemble<<<(TOK * DIM + 255) / 256, 256, 0, stream>>>(qc, cls_token,
                                                          pos_embed, hbuf);

  float* h = hbuf;
  float* acc = accb;
  for (int l = 0; l < NLAYER; ++l) {
    hipMemsetAsync(acc, 0, (size_t)TOK * DIM * sizeof(float), stream);
    hipMemsetAsync(cnt_eb, 0, 256 * sizeof(int), stream);
    k_router<<<TOK, 64, 0, stream>>>(h, router_w + (size_t)l * DIM * NEXP,
                                     router_b + (size_t)l * NEXP, cnt_eb, tmps,
                                     tmpw);
    k_scan<<<1, 64, 0, stream>>>(cnt_eb, off_eb, off_e, cnt_e);
    k_scatter<<<256, 256, 0, stream>>>(cnt_eb, off_eb, tmps, tmpw, ptok, pwb);
    k_ln_noaff<<<TOK, 256, 0, stream>>>(h, xhat);

    const float* Wl = w4 + (size_t)l * NEXP * DIM * 768;
    const float* Bl = b4 + (size_t)l * NEXP * 768;

    // Q: gathered rows, all 8 experts, qkv cols [0,256)
    k_gemm_t<<<dim3(2, YB, 8), 256, 0, stream>>>(
        xhat, Wl, Bl, nullptr, nullptr, nullptr, ptok, off_e, cnt_e, qc, 0,
        DIM, DIM, 768, 0, 768, 0, 0, 3);

    // K/V dense (all tokens) for 4 experts at a time (buffer aliased w/ ffc)
    for (int grp = 0; grp < 2; ++grp) {
      int eb0 = grp * 4;
      k_gemm16<<<dim3(4, YB128, 4), 256, 0, stream>>>(
          xhat, Wl, Bl, nullptr, nullptr, nullptr, nullptr, nullptr, nullptr,
          kv4, TOK, 512, DIM, 768, 256, 768, eb0, 0, 0);
      k_attn<<<1024, 256, 0, stream>>>(qc, kv4, oc, cnt_eb, off_eb, eb0);
    }

    // proj (+ residual h), compact rows
    k_gemm_t<<<dim3(2, YB, 8), 256, 0, stream>>>(
        oc, proj_w + (size_t)l * NEXP * DIM * DIM,
        proj_b + (size_t)l * NEXP * DIM, h, nullptr, nullptr, ptok, off_e,
        cnt_e, x2c, 0, DIM, DIM, DIM, 0, DIM, 0, 1, 1);
    k_ln_seg<<<dim3(YB, 8), 256, 0, stream>>>(
        x2c, ln2_g + (size_t)l * NEXP * DIM, ln2_b + (size_t)l * NEXP * DIM,
        hlnc, off_e, cnt_e);
    k_gemm16<<<dim3(8, YB128, 8), 256, 0, stream>>>(
        hlnc, fc1_w + (size_t)l * NEXP * DIM * FFDIM,
        fc1_b + (size_t)l * NEXP * FFDIM, nullptr, nullptr, nullptr, ptok,
        off_e, cnt_e, ffc, 0, FFDIM, DIM, FFDIM, 0, FFDIM, 0, 2, 1);
    // fc2: weighted scatter-accumulate into acc (2 commutative adds/token)
    k_gemm_t<<<dim3(2, YB, 8), 256, 0, stream>>>(
        ffc, fc2_w + (size_t)l * NEXP * FFDIM * DIM,
        fc2_b + (size_t)l * NEXP * DIM, nullptr, x2c, pwb, ptok, off_e, cnt_e,
        acc, 0, DIM, FFDIM, DIM, 0, DIM, 0, 3, 1);
    float* t = h;
    h = acc;
    acc = t;
  }
  k_head<<<BATCH, 256, 0, stream>>>(h, norm_g, norm_b, head_w, head_b,
                                    (float*)d_out);
}

// Round 17
// 3323.966 us; speedup vs baseline: 1.1397x; 1.1397x over previous
//
#include <hip/hip_runtime.h>
#include <math.h>

#define SEQ 197
#define BATCH 32
#define DIM 256
#define NHEAD 8
#define HDIM 32
#define NEXP 8
#define NLAYER 4
#define FFDIM 1024
#define NCLS 1000
#define NPATCH 196
#define TOK (BATCH * SEQ) /* 6304 */
#define CAP 13120         /* 2*TOK + 8*64 segment padding */
#define YB 99             /* ceil(TOK/64) */
#define YB128 50          /* ceil(TOK/128) */
#define KT 64             /* attention key tile */

// ------------------------------------------------- global->LDS direct DMA ---
__device__ __forceinline__ void gload16(const float* g, float* l) {
  __builtin_amdgcn_global_load_lds(
      (const __attribute__((address_space(1))) void*)g,
      (__attribute__((address_space(3))) void*)l, 16, 0, 0);
}

// ---------------------------------------------------------------- im2col ----
__global__ __launch_bounds__(256) void k_im2col(const float* __restrict__ x,
                                                float* __restrict__ Apat) {
  int idx = blockIdx.x * 256 + threadIdx.x;
  if (idx >= BATCH * NPATCH * 768) return;
  int cpp = idx % 768;
  int m = idx / 768;
  int n = m % NPATCH;
  int b = m / NPATCH;
  int c = cpp >> 8;
  int py = (cpp >> 4) & 15;
  int px = cpp & 15;
  int gy = n / 14, gx = n % 14;
  Apat[idx] = x[(((size_t)b * 3 + c) * 224 + gy * 16 + py) * 224 + gx * 16 + px];
}

// --------------------------------------------- fold ln1 affine into qkv_w ---
__global__ __launch_bounds__(256) void k_foldw(const float* __restrict__ qw,
                                               const float* __restrict__ g1,
                                               float* __restrict__ w4) {
  size_t idx = (size_t)blockIdx.x * 256 + threadIdx.x;
  if (idx >= (size_t)32 * 256 * 768) return;
  size_t kn = idx % (256 * 768);
  int le = (int)(idx / (256 * 768));
  int k = (int)(kn / 768);
  w4[idx] = qw[idx] * g1[le * 256 + k];
}

__global__ __launch_bounds__(256) void k_foldb(const float* __restrict__ qw,
                                               const float* __restrict__ qb,
                                               const float* __restrict__ b1,
                                               float* __restrict__ b4) {
  int le = blockIdx.y;
  int col = blockIdx.x * 256 + threadIdx.x; /* < 768 */
  const float* w = qw + (size_t)le * 256 * 768 + col;
  const float* lb = b1 + (size_t)le * 256;
  float acc = 0.f;
  for (int k = 0; k < 256; ++k) acc = fmaf(lb[k], w[(size_t)k * 768], acc);
  b4[(size_t)le * 768 + col] = acc + qb[(size_t)le * 768 + col];
}

// ------------------------------------------------------------ GEMM (4x8) ----
// 64x128 tile, BK=32, 256 threads, 4x8/thread. BOTH A and B staged by
// global_load_lds DMA. BK=32 halves the barrier/drain count vs BK=16 (the
// seg GEMMs are drain-latency-bound at ~1.4 waves/SIMD): 1024 FMA/thread per
// barrier. A stored as two k-half [64][16] subtiles (row stride 16 -> 2-way
// bank alias = free). B [32][128] reads 2-way = free. Thread owns rows
// ty+16*i. Used for patch/Q/proj/fc2.
// flags bit0 = segmented rows (off_e/cnt_e), bit1 = gather A row via ptok.
// mode 0: out[row] = v   1: out[gr]=v+R[tok]   2: out[gr]=gelu(v)
// mode 3: atomicAdd(out[tok], PW[gr]*(X2[gr]+v))
__global__ __launch_bounds__(256) void k_gemm_t(
    const float* __restrict__ A, const float* __restrict__ W,
    const float* __restrict__ bias, const float* __restrict__ R,
    const float* __restrict__ X2, const float* __restrict__ PW,
    const int* __restrict__ ptok, const int* __restrict__ off_e,
    const int* __restrict__ cnt_e, float* __restrict__ out, int M, int N,
    int K, int Wld, int wcol, int bstride, int ebase, int mode, int flags) {
  __shared__ float As[2][2][64][16]; /* [dbuf][k-half][row][k] */
  __shared__ float Bs[2][32][128];
  int gx = gridDim.x, gy = gridDim.y;
  int nwg = gx * gy * gridDim.z;
  int lin = blockIdx.x + gx * (blockIdx.y + gy * blockIdx.z);
  int q8 = nwg >> 3, r8 = nwg & 7;
  int xcd = lin & 7, jj0 = lin >> 3;
  int nlin = (xcd < r8 ? xcd * (q8 + 1) : r8 * (q8 + 1) + (xcd - r8) * q8) + jj0;
  int bx = nlin % gx;
  int t1 = nlin / gx;
  int by = t1 % gy;
  int bz = t1 / gy;

  int e = ebase + bz;
  bool seg = (flags & 1) != 0;
  int rows = seg ? cnt_e[e] : M;
  int row0 = by * 64;
  if (row0 >= rows) return;
  int col0 = bx * 128;
  int tid = threadIdx.x;
  int wv = tid >> 6, lane = tid & 63;
  int base = seg ? off_e[e] : 0;
  const float* Wp = W + (size_t)e * K * Wld + wcol;
  const float* bp = bias + (size_t)e * bstride + wcol;

  // A DMA: wave wv covers rows row0+wv*16..+15 of each k-half; lane l ->
  // row +(l>>2), k-offset (l&3)*4 (half 1 at +16).
  const float* pA;
  {
    int r = row0 + wv * 16 + (lane >> 2);
    int rc = r < rows ? r : rows - 1; /* rows >= 1 since row0 < rows */
    int gr0 = base + rc;
    int arow = seg ? ((flags & 2) ? ptok[gr0] : gr0) : rc;
    pA = A + (size_t)arow * K + (lane & 3) * 4;
  }
  // B DMA: wave wv stages rows wv*8 + 2c (+ l>>5), c = 0..3; lane l ->
  // col (l&31)*4.
  const float* pB =
      Wp + (size_t)(wv * 8 + (lane >> 5)) * Wld + col0 + (lane & 31) * 4;

  // prologue: stage tile 0 into buffer 0
  gload16(pA, &As[0][0][wv * 16][0]);
  gload16(pA + 16, &As[0][1][wv * 16][0]);
#pragma unroll
  for (int c = 0; c < 4; ++c)
    gload16(pB + (size_t)(c * 2) * Wld, &Bs[0][wv * 8 + c * 2][0]);
  __syncthreads();

  int tx = tid & 15, ty = tid >> 4;
  float acc0[4][4] = {};
  float acc1[4][4] = {};
  int cur = 0;
  for (int k0 = 0; k0 < K; k0 += 32) {
    int nb = cur ^ 1;
    bool more = (k0 + 32) < K;
    if (more) { /* issue next-tile DMA; drained at the barrier below */
      gload16(pA + k0 + 32, &As[nb][0][wv * 16][0]);
      gload16(pA + k0 + 48, &As[nb][1][wv * 16][0]);
#pragma unroll
      for (int c = 0; c < 4; ++c)
        gload16(pB + (size_t)(k0 + 32 + c * 2) * Wld,
                &Bs[nb][wv * 8 + c * 2][0]);
    }
#pragma unroll
    for (int h = 0; h < 2; ++h) {
#pragma unroll
      for (int k4 = 0; k4 < 4; ++k4) {
        float a[4][4];
#pragma unroll
        for (int i = 0; i < 4; ++i) {
          float4 t = *(const float4*)&As[cur][h][ty + 16 * i][k4 * 4];
          a[i][0] = t.x;
          a[i][1] = t.y;
          a[i][2] = t.z;
          a[i][3] = t.w;
        }
#pragma unroll
        for (int kk = 0; kk < 4; ++kk) {
          int kr = h * 16 + k4 * 4 + kk;
          float4 b0 = *(const float4*)&Bs[cur][kr][tx * 4];
          float4 b1 = *(const float4*)&Bs[cur][kr][64 + tx * 4];
          float b0a[4] = {b0.x, b0.y, b0.z, b0.w};
          float b1a[4] = {b1.x, b1.y, b1.z, b1.w};
#pragma unroll
          for (int i = 0; i < 4; ++i) {
            float av = a[i][kk];
#pragma unroll
            for (int j = 0; j < 4; ++j) {
              acc0[i][j] = fmaf(av, b0a[j], acc0[i][j]);
              acc1[i][j] = fmaf(av, b1a[j], acc1[i][j]);
            }
          }
        }
      }
    }
    __syncthreads();
    cur = nb;
  }
#pragma unroll
  for (int i = 0; i < 4; ++i) {
    int rrow = row0 + ty + 16 * i;
    if (rrow >= rows) continue;
    int gr = base + rrow;
#pragma unroll
    for (int c = 0; c < 2; ++c) {
#pragma unroll
      for (int j = 0; j < 4; ++j) {
        int col = col0 + c * 64 + tx * 4 + j;
        float v = (c ? acc1[i][j] : acc0[i][j]) + bp[col];
        if (mode == 0) {
          size_t orow = seg ? (size_t)gr : (size_t)bz * M + rrow;
          out[orow * N + col] = v;
        } else if (mode == 1) {
          int t = ptok[gr];
          out[(size_t)gr * N + col] = v + R[(size_t)t * N + col];
        } else if (mode == 2) {
          out[(size_t)gr * N + col] =
              0.5f * v * (1.f + erff(v * 0.70710678118654752f));
        } else {
          int t = ptok[gr];
          atomicAdd(&out[(size_t)t * N + col],
                    PW[gr] * (X2[(size_t)gr * N + col] + v));
        }
      }
    }
  }
}

// ------------------------------------------------------------ GEMM (16x8) ---
// 128x128x16 tile, 256 threads (4 waves), 8x8/thread. Both A and B staged by
// global_load_lds DMA. Used for the block-rich dense GEMMs: KV / fc1.
__global__ __launch_bounds__(256) void k_gemm16(
    const float* __restrict__ A, const float* __restrict__ W,
    const float* __restrict__ bias, const float* __restrict__ R,
    const float* __restrict__ X2, const float* __restrict__ PW,
    const int* __restrict__ ptok, const int* __restrict__ off_e,
    const int* __restrict__ cnt_e, float* __restrict__ out, int M, int N,
    int K, int Wld, int wcol, int bstride, int ebase, int mode, int flags) {
  __shared__ float As[2][128][16];
  __shared__ float Bs[2][16][128];
  int gx = gridDim.x, gy = gridDim.y;
  int nwg = gx * gy * gridDim.z;
  int lin = blockIdx.x + gx * (blockIdx.y + gy * blockIdx.z);
  int q8 = nwg >> 3, r8 = nwg & 7;
  int xcd = lin & 7, jj0 = lin >> 3;
  int nlin = (xcd < r8 ? xcd * (q8 + 1) : r8 * (q8 + 1) + (xcd - r8) * q8) + jj0;
  int bx = nlin % gx;
  int t1 = nlin / gx;
  int by = t1 % gy;
  int bz = t1 / gy;

  int e = ebase + bz;
  bool seg = (flags & 1) != 0;
  int rows = seg ? cnt_e[e] : M;
  int row0 = by * 128;
  if (row0 >= rows) return;
  int col0 = bx * 128;
  int tid = threadIdx.x;
  int wv = tid >> 6, lane = tid & 63;
  int base = seg ? off_e[e] : 0;
  const float* Wp = W + (size_t)e * K * Wld + wcol;
  const float* bp = bias + (size_t)e * bstride + wcol;

  const float* pA0;
  const float* pA1;
  {
    int l4 = lane >> 2, lk = (lane & 3) * 4;
#pragma unroll
    for (int c = 0; c < 2; ++c) {
      int r = row0 + wv * 32 + c * 16 + l4;
      int rc = r < rows ? r : rows - 1;
      int gr0 = base + rc;
      int arow = seg ? ((flags & 2) ? ptok[gr0] : gr0) : rc;
      const float* p = A + (size_t)arow * K + lk;
      if (c == 0) pA0 = p; else pA1 = p;
    }
  }
  const float* pB = Wp + (size_t)(4 * wv + (lane >> 5)) * Wld + col0 +
                    (lane & 31) * 4;

  gload16(pA0, &As[0][wv * 32][0]);
  gload16(pA1, &As[0][wv * 32 + 16][0]);
  gload16(pB, &Bs[0][4 * wv][0]);
  gload16(pB + (size_t)2 * Wld, &Bs[0][4 * wv + 2][0]);
  __syncthreads();

  int tx = tid & 15, ty = tid >> 4; /* ty 0..15 */
  float acc0[8][4] = {};
  float acc1[8][4] = {};
  int cur = 0;
  for (int k0 = 0; k0 < K; k0 += 16) {
    int nb = cur ^ 1;
    bool more = (k0 + 16) < K;
    if (more) {
      gload16(pA0 + k0 + 16, &As[nb][wv * 32][0]);
      gload16(pA1 + k0 + 16, &As[nb][wv * 32 + 16][0]);
      gload16(pB + (size_t)(k0 + 16) * Wld, &Bs[nb][4 * wv][0]);
      gload16(pB + (size_t)(k0 + 18) * Wld, &Bs[nb][4 * wv + 2][0]);
    }
#pragma unroll
    for (int k4 = 0; k4 < 4; ++k4) {
      float a[8][4];
#pragma unroll
      for (int i = 0; i < 8; ++i) {
        float4 t = *(const float4*)&As[cur][ty + 16 * i][k4 * 4];
        a[i][0] = t.x;
        a[i][1] = t.y;
        a[i][2] = t.z;
        a[i][3] = t.w;
      }
#pragma unroll
      for (int kk = 0; kk < 4; ++kk) {
        float4 b0 = *(const float4*)&Bs[cur][k4 * 4 + kk][tx * 4];
        float4 b1 = *(const float4*)&Bs[cur][k4 * 4 + kk][64 + tx * 4];
        float b0a[4] = {b0.x, b0.y, b0.z, b0.w};
        float b1a[4] = {b1.x, b1.y, b1.z, b1.w};
#pragma unroll
        for (int i = 0; i < 8; ++i) {
          float av = a[i][kk];
#pragma unroll
          for (int j = 0; j < 4; ++j) {
            acc0[i][j] = fmaf(av, b0a[j], acc0[i][j]);
            acc1[i][j] = fmaf(av, b1a[j], acc1[i][j]);
          }
        }
      }
    }
    __syncthreads();
    cur = nb;
  }
#pragma unroll
  for (int i = 0; i < 8; ++i) {
    int rrow = row0 + ty + 16 * i;
    if (rrow >= rows) continue;
    int gr = base + rrow;
#pragma unroll
    for (int c = 0; c < 2; ++c) {
#pragma unroll
      for (int j = 0; j < 4; ++j) {
        int col = col0 + c * 64 + tx * 4 + j;
        float v = (c ? acc1[i][j] : acc0[i][j]) + bp[col];
        if (mode == 0) {
          size_t orow = seg ? (size_t)gr : (size_t)bz * M + rrow;
          out[orow * N + col] = v;
        } else if (mode == 1) {
          int t = ptok[gr];
          out[(size_t)gr * N + col] = v + R[(size_t)t * N + col];
        } else if (mode == 2) {
          out[(size_t)gr * N + col] =
              0.5f * v * (1.f + erff(v * 0.70710678118654752f));
        } else {
          int t = ptok[gr];
          atomicAdd(&out[(size_t)t * N + col],
                    PW[gr] * (X2[(size_t)gr * N + col] + v));
        }
      }
    }
  }
}

// ------------------------------------------------------------- assemble h ---
__global__ __launch_bounds__(256) void k_assemble(const float* __restrict__ tmp,
                                                  const float* __restrict__ cls,
                                                  const float* __restrict__ pos,
                                                  float* __restrict__ h) {
  int idx = blockIdx.x * 256 + threadIdx.x;
  if (idx >= TOK * DIM) return;
  int d = idx & 255;
  int t = idx >> 8;
  int s = t % SEQ;
  int b = t / SEQ;
  float v = (s == 0) ? cls[d] : tmp[((size_t)b * NPATCH + s - 1) * DIM + d];
  h[idx] = v + pos[s * DIM + d];
}

// ------------------------------------------------------------------ router --
__global__ __launch_bounds__(64) void k_router(
    const float* __restrict__ h, const float* __restrict__ rw,
    const float* __restrict__ rb, int* __restrict__ cnt_eb,
    int* __restrict__ tmp_s, float* __restrict__ tmp_w) {
  int t = blockIdx.x;
  int lane = threadIdx.x;
  float hv[4];
  const float* hp = h + (size_t)t * DIM + lane * 4;
#pragma unroll
  for (int i = 0; i < 4; i++) hv[i] = hp[i];
  float lg[8];
#pragma unroll
  for (int e = 0; e < 8; e++) {
    float p = 0.f;
#pragma unroll
    for (int i = 0; i < 4; i++) p = fmaf(hv[i], rw[(lane * 4 + i) * 8 + e], p);
#pragma unroll
    for (int off = 32; off; off >>= 1) p += __shfl_down(p, off);
    lg[e] = p;
  }
  if (lane == 0) {
#pragma unroll
    for (int e = 0; e < 8; e++) lg[e] += rb[e];
    float mx = lg[0];
#pragma unroll
    for (int e = 1; e < 8; e++) mx = fmaxf(mx, lg[e]);
    float pr[8];
#pragma unroll
    for (int e = 0; e < 8; e++) pr[e] = expf(lg[e] - mx);
    int i0 = 0;
#pragma unroll
    for (int e = 1; e < 8; e++)
      if (pr[e] > pr[i0]) i0 = e;
    int i1 = -1;
#pragma unroll
    for (int e = 0; e < 8; e++)
      if (e != i0 && (i1 < 0 || pr[e] > pr[i1])) i1 = e;
    float wsum = pr[i0] + pr[i1];
    int b = t / SEQ, s = t - b * SEQ;
    int eb0 = i0 * 32 + b;
    int p0 = atomicAdd(&cnt_eb[eb0], 1);
    tmp_s[eb0 * SEQ + p0] = s;
    tmp_w[eb0 * SEQ + p0] = pr[i0] / wsum;
    int eb1 = i1 * 32 + b;
    int p1 = atomicAdd(&cnt_eb[eb1], 1);
    tmp_s[eb1 * SEQ + p1] = s;
    tmp_w[eb1 * SEQ + p1] = pr[i1] / wsum;
  }
}

// --------------------------------------------------------------- scan -------
__global__ __launch_bounds__(64) void k_scan(const int* __restrict__ cnt_eb,
                                             int* __restrict__ off_eb,
                                             int* __restrict__ off_e,
                                             int* __restrict__ cnt_e) {
  if (threadIdx.x == 0 && blockIdx.x == 0) {
    int g = 0;
    for (int e = 0; e < 8; e++) {
      off_e[e] = g;
      int ce = 0;
      for (int b = 0; b < 32; b++) {
        off_eb[e * 32 + b] = g + ce;
        ce += cnt_eb[e * 32 + b];
      }
      cnt_e[e] = ce;
      g += (ce + 63) & ~63;
    }
  }
}

__global__ __launch_bounds__(256) void k_scatter(
    const int* __restrict__ cnt_eb, const int* __restrict__ off_eb,
    const int* __restrict__ tmp_s, const float* __restrict__ tmp_w,
    int* __restrict__ ptok, float* __restrict__ pw) {
  int eb = blockIdx.x;
  int b = eb & 31;
  int c = cnt_eb[eb];
  int o = off_eb[eb];
  for (int i = threadIdx.x; i < c; i += 256) {
    ptok[o + i] = b * SEQ + tmp_s[eb * SEQ + i];
    pw[o + i] = tmp_w[eb * SEQ + i];
  }
}

// -------------------------------------------------------------- layernorm ---
__global__ __launch_bounds__(256) void k_ln_noaff(const float* __restrict__ X,
                                                  float* __restrict__ Y) {
  int t = blockIdx.x;
  int d = threadIdx.x;
  float v = X[(size_t)t * DIM + d];
  __shared__ float red[4];
  float s = v;
#pragma unroll
  for (int o = 32; o; o >>= 1) s += __shfl_down(s, o);
  if ((d & 63) == 0) red[d >> 6] = s;
  __syncthreads();
  float mean = (red[0] + red[1] + red[2] + red[3]) * (1.f / 256.f);
  __syncthreads();
  float c = v - mean;
  float s2 = c * c;
#pragma unroll
  for (int o = 32; o; o >>= 1) s2 += __shfl_down(s2, o);
  if ((d & 63) == 0) red[d >> 6] = s2;
  __syncthreads();
  float var = (red[0] + red[1] + red[2] + red[3]) * (1.f / 256.f);
  Y[(size_t)t * DIM + d] = c * rsqrtf(var + 1e-5f);
}

__global__ __launch_bounds__(256) void k_ln_seg(
    const float* __restrict__ X, const float* __restrict__ g,
    const float* __restrict__ bta, float* __restrict__ Y,
    const int* __restrict__ off_e, const int* __restrict__ cnt_e) {
  int e = blockIdx.y;
  int cnt = cnt_e[e];
  int base = off_e[e];
  int d = threadIdx.x;
  float gv = g[e * DIM + d];
  float bv = bta[e * DIM + d];
  __shared__ float red[4];
  for (int r = blockIdx.x; r < cnt; r += gridDim.x) {
    size_t gr = (size_t)(base + r);
    float v = X[gr * DIM + d];
    float s = v;
#pragma unroll
    for (int o = 32; o; o >>= 1) s += __shfl_down(s, o);
    if ((d & 63) == 0) red[d >> 6] = s;
    __syncthreads();
    float mean = (red[0] + red[1] + red[2] + red[3]) * (1.f / 256.f);
    __syncthreads();
    float c = v - mean;
    float s2 = c * c;
#pragma unroll
    for (int o = 32; o; o >>= 1) s2 += __shfl_down(s2, o);
    if ((d & 63) == 0) red[d >> 6] = s2;
    __syncthreads();
    float var = (red[0] + red[1] + red[2] + red[3]) * (1.f / 256.f);
    Y[gr * DIM + d] = c * rsqrtf(var + 1e-5f) * gv + bv;
    __syncthreads();
  }
}

// -------------------------------------------------------------- attention ---
// block = (expert-slot, batch, head). K/V staged in 64-key LDS tiles (16 KB
// -> 8 blocks/CU). 4-lane quad per query; branchless online softmax.
__global__ __launch_bounds__(256) void k_attn(
    const float* __restrict__ qc, const float* __restrict__ kv,
    float* __restrict__ oc, const int* __restrict__ cnt_eb,
    const int* __restrict__ off_eb, int ebase) {
  int bx = blockIdx.x;
  int hh = bx & 7;
  int b = (bx >> 3) & 31;
  int ez = bx >> 8;
  int eb = (ebase + ez) * 32 + b;
  int cnt = cnt_eb[eb];
  if (cnt == 0) return;
  int off = off_eb[eb];
  __shared__ float Ks[KT][HDIM];
  __shared__ float Vs[KT][HDIM];
  const float* base = kv + ((size_t)ez * TOK + (size_t)b * SEQ) * 512;
  int tid = threadIdx.x;
  int grp = tid >> 2; /* 0..63 query slot */
  int ln = tid & 3;   /* quad lane: dims [ln*8, ln*8+8) */
  int nrounds = (cnt + 63) >> 6;
  for (int qr = 0; qr < nrounds; ++qr) {
    int qi = qr * 64 + grp;
    bool act = qi < cnt;
    int qc_i = act ? qi : cnt - 1;
    const float* qp = qc + (size_t)(off + qc_i) * DIM + hh * HDIM + ln * 8;
    float4 q0 = *(const float4*)qp;
    float4 q1 = *(const float4*)(qp + 4);
    float qv[8] = {q0.x, q0.y, q0.z, q0.w, q1.x, q1.y, q1.z, q1.w};
    float m = -1e30f, l = 0.f;
    float acc[8] = {};
    for (int t0 = 0; t0 < SEQ; t0 += KT) {
      int nk = (SEQ - t0) < KT ? (SEQ - t0) : KT;
      __syncthreads();
      for (int i = tid; i < nk * 16; i += 256) {
        int row = i >> 4, half = (i >> 3) & 1, c4 = (i & 7) * 4;
        const float* p =
            base + (size_t)(t0 + row) * 512 + half * 256 + hh * HDIM + c4;
        if (half == 0)
          *(float4*)&Ks[row][c4] = *(const float4*)p;
        else
          *(float4*)&Vs[row][c4] = *(const float4*)p;
      }
      __syncthreads();
      const float* KsL = &Ks[0][ln * 8];
      const float* VsL = &Vs[0][ln * 8];
#pragma unroll 2
      for (int j = 0; j < nk; ++j) {
        const float4* kr = (const float4*)(KsL + j * HDIM);
        float4 k0 = kr[0], k1 = kr[1];
        float s = qv[0] * k0.x;
        s = fmaf(qv[1], k0.y, s);
        s = fmaf(qv[2], k0.z, s);
        s = fmaf(qv[3], k0.w, s);
        s = fmaf(qv[4], k1.x, s);
        s = fmaf(qv[5], k1.y, s);
        s = fmaf(qv[6], k1.z, s);
        s = fmaf(qv[7], k1.w, s);
        s += __shfl_xor(s, 1);
        s += __shfl_xor(s, 2);
        s *= 0.17677669529663687f; /* 1/sqrt(32) */
        float nm = fmaxf(m, s);
        float f = expf(m - nm);
        float e2 = expf(s - nm);
        m = nm;
        l = fmaf(l, f, e2);
        const float4* vr = (const float4*)(VsL + j * HDIM);
        float4 v0 = vr[0], v1 = vr[1];
        acc[0] = fmaf(acc[0], f, e2 * v0.x);
        acc[1] = fmaf(acc[1], f, e2 * v0.y);
        acc[2] = fmaf(acc[2], f, e2 * v0.z);
        acc[3] = fmaf(acc[3], f, e2 * v0.w);
        acc[4] = fmaf(acc[4], f, e2 * v1.x);
        acc[5] = fmaf(acc[5], f, e2 * v1.y);
        acc[6] = fmaf(acc[6], f, e2 * v1.z);
        acc[7] = fmaf(acc[7], f, e2 * v1.w);
      }
    }
    if (act) {
      float inv = 1.f / l;
      float* op = oc + (size_t)(off + qi) * DIM + hh * HDIM + ln * 8;
      float4 o0 = {acc[0] * inv, acc[1] * inv, acc[2] * inv, acc[3] * inv};
      float4 o1 = {acc[4] * inv, acc[5] * inv, acc[6] * inv, acc[7] * inv};
      *(float4*)op = o0;
      *(float4*)(op + 4) = o1;
    }
  }
}

// ------------------------------------------------------------- final head ---
__global__ __launch_bounds__(256) void k_head(const float* __restrict__ h,
                                              const float* __restrict__ ng,
                                              const float* __restrict__ nb,
                                              const float* __restrict__ hw,
                                              const float* __restrict__ hb,
                                              float* __restrict__ out) {
  int b = blockIdx.x;
  int d = threadIdx.x;
  float v = h[(size_t)b * SEQ * DIM + d];
  __shared__ float red[4];
  __shared__ float hls[DIM];
  float s = v;
#pragma unroll
  for (int off = 32; off; off >>= 1) s += __shfl_down(s, off);
  if ((d & 63) == 0) red[d >> 6] = s;
  __syncthreads();
  float mean = (red[0] + red[1] + red[2] + red[3]) * (1.f / 256.f);
  __syncthreads();
  float c = v - mean;
  float s2 = c * c;
#pragma unroll
  for (int off = 32; off; off >>= 1) s2 += __shfl_down(s2, off);
  if ((d & 63) == 0) red[d >> 6] = s2;
  __syncthreads();
  float var = (red[0] + red[1] + red[2] + red[3]) * (1.f / 256.f);
  hls[d] = c * rsqrtf(var + 1e-5f) * ng[d] + nb[d];
  __syncthreads();
  for (int j = d; j < NCLS; j += 256) {
    float sdot = hb[j];
    for (int k2 = 0; k2 < DIM; k2++)
      sdot = fmaf(hls[k2], hw[(size_t)k2 * NCLS + j], sdot);
    out[(size_t)b * NCLS + j] = sdot;
  }
}

// ---------------------------------------------------------------- launch ----
extern "C" void kernel_launch(void* const* d_in, const int* in_sizes, int n_in,
                              void* d_out, int out_size, void* d_ws,
                              size_t ws_size, hipStream_t stream) {
  const float* x = (const float*)d_in[0];
  const float* patch_w = (const float*)d_in[1];
  const float* patch_b = (const float*)d_in[2];
  const float* cls_token = (const float*)d_in[3];
  const float* pos_embed = (const float*)d_in[4];
  const float* router_w = (const float*)d_in[5];
  const float* router_b = (const float*)d_in[6];
  const float* ln1_g = (const float*)d_in[7];
  const float* ln1_b = (const float*)d_in[8];
  const float* qkv_w = (const float*)d_in[9];
  const float* qkv_b = (const float*)d_in[10];
  const float* proj_w = (const float*)d_in[11];
  const float* proj_b = (const float*)d_in[12];
  const float* ln2_g = (const float*)d_in[13];
  const float* ln2_b = (const float*)d_in[14];
  const float* fc1_w = (const float*)d_in[15];
  const float* fc1_b = (const float*)d_in[16];
  const float* fc2_w = (const float*)d_in[17];
  const float* fc2_b = (const float*)d_in[18];
  const float* norm_g = (const float*)d_in[19];
  const float* norm_b = (const float*)d_in[20];
  const float* head_w = (const float*)d_in[21];
  const float* head_b = (const float*)d_in[22];

  float* ws = (float*)d_ws;
  size_t off = 0;
  float* xhat = ws + off; off += (size_t)TOK * DIM;
  float* hbuf = ws + off; off += (size_t)TOK * DIM;
  float* accb = ws + off; off += (size_t)TOK * DIM;
  float* qc   = ws + off; off += (size_t)CAP * DIM;   /* also hln (aliased) */
  float* oc   = ws + off; off += (size_t)CAP * DIM;
  float* x2c  = ws + off; off += (size_t)CAP * DIM;
  float* ffc  = ws + off; off += (size_t)CAP * FFDIM; /* also im2col + kv4 */
  float* w4   = ws + off; off += (size_t)32 * DIM * 768; /* folded qkv W */
  float* b4   = ws + off; off += (size_t)32 * 768;       /* folded qkv b */
  float* pwb  = ws + off; off += CAP;
  float* tmpw = ws + off; off += 256 * SEQ;
  int* ptok   = (int*)(ws + off); off += CAP;
  int* tmps   = (int*)(ws + off); off += 256 * SEQ;
  int* cnt_eb = (int*)(ws + off); off += 256;
  int* off_eb = (int*)(ws + off); off += 256;
  int* off_e  = (int*)(ws + off); off += 8;
  int* cnt_e  = (int*)(ws + off); off += 8;
  float* kv4 = ffc;   /* 4*TOK*512 = 12.9M floats <= CAP*FFDIM = 13.4M */
  float* hlnc = qc;   /* qc dead after attention; hln live ln2->fc1 */

  // ---- one-time: fold ln1 affine into qkv weights ----
  k_foldw<<<(32 * 256 * 768 + 255) / 256, 256, 0, stream>>>(qkv_w, ln1_g, w4);
  k_foldb<<<dim3(3, 32), 256, 0, stream>>>(qkv_w, qkv_b, ln1_b, b4);

  // ---- patch embed ----
  int tot = BATCH * NPATCH * 768;
  k_im2col<<<(tot + 255) / 256, 256, 0, stream>>>(x, ffc);
  k_gemm_t<<<dim3(2, 98, 1), 256, 0, stream>>>(
      ffc, patch_w, patch_b, nullptr, nullptr, nullptr, nullptr, nullptr,
      nullptr, qc, BATCH * NPATCH, DIM, 768, DIM, 0, 0, 0, 0, 0);
  k_assemble<<<(TOK * DIM + 255) / 256, 256, 0, stream>>>(qc, cls_token,
                                                          pos_embed, hbuf);

  float* h = hbuf;
  float* acc = accb;
  for (int l = 0; l < NLAYER; ++l) {
    hipMemsetAsync(acc, 0, (size_t)TOK * DIM * sizeof(float), stream);
    hipMemsetAsync(cnt_eb, 0, 256 * sizeof(int), stream);
    k_router<<<TOK, 64, 0, stream>>>(h, router_w + (size_t)l * DIM * NEXP,
                                     router_b + (size_t)l * NEXP, cnt_eb, tmps,
                                     tmpw);
    k_scan<<<1, 64, 0, stream>>>(cnt_eb, off_eb, off_e, cnt_e);
    k_scatter<<<256, 256, 0, stream>>>(cnt_eb, off_eb, tmps, tmpw, ptok, pwb);
    k_ln_noaff<<<TOK, 256, 0, stream>>>(h, xhat);

    const float* Wl = w4 + (size_t)l * NEXP * DIM * 768;
    const float* Bl = b4 + (size_t)l * NEXP * 768;

    // Q: gathered rows, all 8 experts, qkv cols [0,256)
    k_gemm_t<<<dim3(2, YB, 8), 256, 0, stream>>>(
        xhat, Wl, Bl, nullptr, nullptr, nullptr, ptok, off_e, cnt_e, qc, 0,
        DIM, DIM, 768, 0, 768, 0, 0, 3);

    // K/V dense (all tokens) for 4 experts at a time (buffer aliased w/ ffc)
    for (int grp = 0; grp < 2; ++grp) {
      int eb0 = grp * 4;
      k_gemm16<<<dim3(4, YB128, 4), 256, 0, stream>>>(
          xhat, Wl, Bl, nullptr, nullptr, nullptr, nullptr, nullptr, nullptr,
          kv4, TOK, 512, DIM, 768, 256, 768, eb0, 0, 0);
      k_attn<<<1024, 256, 0, stream>>>(qc, kv4, oc, cnt_eb, off_eb, eb0);
    }

    // proj (+ residual h), compact rows
    k_gemm_t<<<dim3(2, YB, 8), 256, 0, stream>>>(
        oc, proj_w + (size_t)l * NEXP * DIM * DIM,
        proj_b + (size_t)l * NEXP * DIM, h, nullptr, nullptr, ptok, off_e,
        cnt_e, x2c, 0, DIM, DIM, DIM, 0, DIM, 0, 1, 1);
    k_ln_seg<<<dim3(YB, 8), 256, 0, stream>>>(
        x2c, ln2_g + (size_t)l * NEXP * DIM, ln2_b + (size_t)l * NEXP * DIM,
        hlnc, off_e, cnt_e);
    k_gemm16<<<dim3(8, YB128, 8), 256, 0, stream>>>(
        hlnc, fc1_w + (size_t)l * NEXP * DIM * FFDIM,
        fc1_b + (size_t)l * NEXP * FFDIM, nullptr, nullptr, nullptr, ptok,
        off_e, cnt_e, ffc, 0, FFDIM, DIM, FFDIM, 0, FFDIM, 0, 2, 1);
    // fc2: weighted scatter-accumulate into acc (2 commutative adds/token)
    k_gemm_t<<<dim3(2, YB, 8), 256, 0, stream>>>(
        ffc, fc2_w + (size_t)l * NEXP * FFDIM * DIM,
        fc2_b + (size_t)l * NEXP * DIM, nullptr, x2c, pwb, ptok, off_e, cnt_e,
        acc, 0, DIM, FFDIM, DIM, 0, DIM, 0, 3, 1);
    float* t = h;
    h = acc;
    acc = t;
  }
  k_head<<<BATCH, 256, 0, stream>>>(h, norm_g, norm_b, head_w, head_b,
                                    (float*)d_out);
}